// Round 11
// baseline (8017.754 us; speedup 1.0000x reference)
//
#include <hip/hip_runtime.h>
#include <math.h>

#define BB 8
#define TT 12
#define HH 128
#define WW 128
#define FF 64
#define GG 256   // 4*FF
#define PRED_LEN 6
#define TW 64     // pixels per block along W (step kernel)
#define TWD 32    // pixels per block along W (decoder)

typedef __attribute__((ext_vector_type(8))) short short8;
typedef __attribute__((ext_vector_type(4))) float floatx4;

__device__ __forceinline__ float sigf(float x) { return 1.f / (1.f + __expf(-x)); }
__device__ __forceinline__ float tanhfast(float x) { return 1.f - 2.f / (__expf(2.f * x) + 1.f); }

__device__ __forceinline__ unsigned short f2bf(float x) {
    unsigned u = __float_as_uint(x);
    u = (u + 0x7FFFu + ((u >> 16) & 1u)) >> 16;
    return (unsigned short)u;
}

// Step-grid XCD swizzle: 1024 blocks, one batch per XCD, y-contiguous
// (R8-proven L2 locality). 1024 = 4 x 256 CUs and 34.9KB LDS -> ALL blocks
// co-resident (R10: kills the 3-then-1 tail that capped occupancy at 33%).
__device__ __forceinline__ void decode_step(int wg, int& b, int& y, int& x0) {
    int lin = (wg & 7) * 128 + (wg >> 3);   // [0,1024)
    b = lin >> 7;                           // 128 blocks per batch
    int rem = lin & 127;
    y = (rem >> 1) * 2;                     // y-pair base row
    x0 = (rem & 1) * TW;
}

// Decoder swizzle (R6/R7-proven): 4096 blocks.
__device__ __forceinline__ void decode_dec(int wg, int& b, int& y, int& x0) {
    int lin = (wg & 7) * 512 + (wg >> 3);
    b = lin >> 9;
    int rem = lin & 511;
    y = rem >> 2;
    x0 = (rem & 3) * TWD;
}

// Pack B-fragments for mfma_f32_16x16x32_bf16.  (R5-proven, unchanged.)
// Chunks 0..17 (wr): c = tap*2+kc; lane = col + 16*kpart holds B[k][n],
//   k = kc*32 + kpart*8 + j, n = nt*16 + col.
// Chunk 18 (x-conv + bias): B[k][n] = k<9 ? wk[k][n] : k==9 ? bias[n] : 0.
__global__ __launch_bounds__(256) void pack_wr(
    const float* __restrict__ wr, const float* __restrict__ wk,
    const float* __restrict__ bias, short8* __restrict__ packed)
{
    int e = blockIdx.x * 256 + threadIdx.x;   // 19456 entries
    if (e >= 19 * 16 * 64) return;
    int lane = e & 63;
    int rest = e >> 6;
    int nt = rest & 15;
    int ch = rest >> 4;        // 0..18
    int col = lane & 15, kpart = lane >> 4;
    int n = nt * 16 + col;
    short8 v;
    if (ch < 18) {
        int kc = ch & 1, tap = ch >> 1;
        #pragma unroll
        for (int j = 0; j < 8; ++j) {
            int k = kc * 32 + kpart * 8 + j;
            v[j] = (short)f2bf(wr[((size_t)(tap * 64 + k)) * GG + n]);
        }
    } else {
        #pragma unroll
        for (int j = 0; j < 8; ++j) {
            int k = kpart * 8 + j;
            unsigned short r = 0;
            if (k < 9) r = f2bf(wk[k * GG + n]);
            else if (k == 9) r = f2bf(bias[n]);   // bias row (A has 1.0 there)
            v[j] = (short)r;
        }
    }
    packed[e] = v;
}

// Fused ConvLSTM step, double-row blocks (R9) + full co-residency (R10).
// Block = 512 threads = 8 waves: waves 0-3 row y, waves 4-7 row y+1 with
// IDENTICAL packedB addresses (weight stream amortized 2x, R9-proven).
// LDS trimmed to ~35KB (sxa tile removed; chunk-18 A-frags built inline
// from the fp32 sx tile) -> 4 blocks/CU = 32 waves/CU = HW max.
template<bool FIRST>
__global__ __launch_bounds__(512, 8) void lstm_step_mfma(
    const float* __restrict__ x,             // (B,T,H,W,1) fp32
    int t,
    const unsigned short* __restrict__ h_in, // (B,H,W,F) bf16
    float* __restrict__ c_buf,               // (B,H,W,F) fp32 in/out
    unsigned short* __restrict__ h_out,      // (B,H,W,F) bf16
    const short8* __restrict__ packedB)      // packed wr | wk+bias
{
    __shared__ __align__(16) unsigned short sh[4 * 66 * FF];  // swizzled bf16 h, rows y-1..y+2
    __shared__ float sx[4][66];                               // fp32 x tile

    const int tid = threadIdx.x;
    int b, y, x0;
    decode_step(blockIdx.x, b, y, x0);
    char* shb = (char*)sh;

    if (!FIRST) {
        // stage h tile: 4 rows x 66 cols x 64 ch bf16, 16B chunks, XOR-swizzled
        for (int i = tid; i < 4 * 66 * 8; i += 512) {
            int cq  = i & 7;
            int rc  = i >> 3;
            int col = rc % 66, r = rc / 66;
            int gy = y + r - 1, gx = x0 + col - 1;
            uint4 v = make_uint4(0u, 0u, 0u, 0u);
            if ((unsigned)gy < HH && (unsigned)gx < WW)
                v = *(const uint4*)(h_in + ((((size_t)b * HH + gy) * WW + gx) * FF + cq * 8));
            int byte = ((r * 66 + col) * FF + cq * 8) * 2;
            byte ^= ((col & 7) << 4);
            *(uint4*)(shb + byte) = v;
        }
    }
    // stage x tile (fp32), 4 rows
    for (int i = tid; i < 4 * 66; i += 512) {
        int col = i % 66, r = i / 66;
        int gy = y + r - 1, gx = x0 + col - 1;
        float v = 0.f;
        if ((unsigned)gy < HH && (unsigned)gx < WW)
            v = x[(((size_t)b * TT + t) * HH + gy) * WW + gx];
        sx[r][col] = v;
    }
    __syncthreads();

    const int l    = tid & 63;
    const int w    = tid >> 6;     // 0..7
    const int sw   = w & 3;        // sub-wave role (R8's wave id)
    const int rrow = w >> 2;       // which row of the pair
    const int lc = l & 15;
    const int kp = l >> 4;
    const int gcol = sw * 16 + lc;   // feature index 0..63
    const size_t base = (((size_t)b * HH + (y + rrow)) * WW + x0) * FF + gcol;

    // hoist c-state loads: independent of acc, latency hides under 19 chunks
    float cp[4][4];
    if (!FIRST) {
        #pragma unroll
        for (int m = 0; m < 4; ++m)
            #pragma unroll
            for (int r = 0; r < 4; ++r)
                cp[m][r] = c_buf[base + (size_t)(m * 16 + kp * 4 + r) * FF];
    }

    floatx4 acc[4][4];
    #pragma unroll
    for (int m = 0; m < 4; ++m)
        #pragma unroll
        for (int q = 0; q < 4; ++q)
            acc[m][q] = (floatx4){0.f, 0.f, 0.f, 0.f};

    if (!FIRST) {
        // recurrent conv: 18 chunks, single-buffered (R4/R5-proven)
        #pragma unroll
        for (int c = 0; c < 18; ++c) {
            const int tap_ = c >> 1, kc_ = c & 1, dy_ = tap_ / 3, dx_ = tap_ % 3;
            short8 af[4], bf[4];
            #pragma unroll
            for (int m_ = 0; m_ < 4; ++m_) {
                const int col_ = m_ * 16 + lc + dx_;
                int byte_ = (((dy_ + rrow) * 66 + col_) * FF + kc_ * 32 + kp * 8) * 2;
                byte_ ^= ((col_ & 7) << 4);
                af[m_] = *(const short8*)(shb + byte_);
            }
            #pragma unroll
            for (int q_ = 0; q_ < 4; ++q_)
                bf[q_] = packedB[(size_t)(c * 16 + (q_ * 4 + sw)) * 64 + l];
            #pragma unroll
            for (int m_ = 0; m_ < 4; ++m_)
                #pragma unroll
                for (int q_ = 0; q_ < 4; ++q_)
                    acc[m_][q_] = __builtin_amdgcn_mfma_f32_16x16x32_bf16(
                        af[m_], bf[q_], acc[m_][q_], 0, 0, 0);
        }
    }
    {
        // chunk 18: input conv + bias; A-frags built inline from sx
        // (af[px][k] = k<9 ? x-tap k : k==9 ? 1.0 : 0 -- identical values to
        //  the R9 sxa tile, just no LDS staging)
        short8 af[4], bf[4];
        #pragma unroll
        for (int m_ = 0; m_ < 4; ++m_) {
            const int px_ = m_ * 16 + lc;
            #pragma unroll
            for (int j8 = 0; j8 < 8; ++j8) {
                int k = kp * 8 + j8;
                float xv = 0.f;
                if (k < 9) xv = sx[rrow + k / 3][px_ + (k % 3)];
                else if (k == 9) xv = 1.0f;   // 1.0 multiplies bias row
                af[m_][j8] = (short)f2bf(xv);
            }
        }
        #pragma unroll
        for (int q_ = 0; q_ < 4; ++q_)
            bf[q_] = packedB[(size_t)(18 * 16 + (q_ * 4 + sw)) * 64 + l];
        #pragma unroll
        for (int m_ = 0; m_ < 4; ++m_)
            #pragma unroll
            for (int q_ = 0; q_ < 4; ++q_)
                acc[m_][q_] = __builtin_amdgcn_mfma_f32_16x16x32_bf16(
                    af[m_], bf[q_], acc[m_][q_], 0, 0, 0);
    }

    // epilogue: gates + cell update only (Keras order i,f,g,o)
    #pragma unroll
    for (int m = 0; m < 4; ++m) {
        #pragma unroll
        for (int r = 0; r < 4; ++r) {
            int p = m * 16 + kp * 4 + r;   // pixel within tile
            size_t idx = base + (size_t)p * FF;
            float cpv = FIRST ? 0.f : cp[m][r];
            float iv = sigf(acc[m][0][r]);
            float fv = sigf(acc[m][1][r]);
            float gv = tanhfast(acc[m][2][r]);
            float ov = sigf(acc[m][3][r]);
            float cn = fv * cpv + iv * gv;
            float hn = ov * tanhfast(cn);
            c_buf[idx] = cn;
            h_out[idx] = f2bf(hn);
        }
    }
}

// Fused decoder iteration (R6/R7-proven):
//   pred = sigmoid(conv3x3(cur_in, w_out) + b_out)  -> out[:, ti]
//   cur_out = relu(pred * w_proj + b_proj)          (bf16)
__global__ __launch_bounds__(256) void dec_fused(
    const unsigned short* __restrict__ cur_in, const float* __restrict__ w_out,
    const float* __restrict__ b_out, const float* __restrict__ w_proj,
    const float* __restrict__ b_proj, float* __restrict__ out,
    unsigned short* __restrict__ cur_out, int ti)
{
    int tid = threadIdx.x;
    int j  = tid & 7;
    int pp = tid >> 3;
    int b, y, x0;
    decode_dec(blockIdx.x, b, y, x0);
    int xx = x0 + pp;

    float s = 0.f;
    for (int dy = 0; dy < 3; ++dy) {
        int gy = y + dy - 1;
        if ((unsigned)gy >= HH) continue;
        #pragma unroll
        for (int dx = 0; dx < 3; ++dx) {
            int gx = xx + dx - 1;
            if ((unsigned)gx >= WW) continue;
            const uint4 cv = *(const uint4*)(cur_in + ((((size_t)b * HH + gy) * WW + gx) * FF + j * 8));
            const float4* wp = (const float4*)&w_out[(dy * 3 + dx) * FF + j * 8];
            float4 w0 = wp[0], w1 = wp[1];
            unsigned cx = cv.x, cy = cv.y, cz = cv.z, cw = cv.w;
            s += __uint_as_float(cx << 16) * w0.x + __uint_as_float(cx & 0xFFFF0000u) * w0.y
               + __uint_as_float(cy << 16) * w0.z + __uint_as_float(cy & 0xFFFF0000u) * w0.w
               + __uint_as_float(cz << 16) * w1.x + __uint_as_float(cz & 0xFFFF0000u) * w1.y
               + __uint_as_float(cw << 16) * w1.z + __uint_as_float(cw & 0xFFFF0000u) * w1.w;
        }
    }
    s += __shfl_xor(s, 1);
    s += __shfl_xor(s, 2);
    s += __shfl_xor(s, 4);
    float pv = sigf(s + b_out[0]);

    size_t pix = (((size_t)b * HH + y) * WW + xx);
    if (j == 0)
        out[((size_t)b * PRED_LEN + ti) * (HH * WW) + (size_t)y * WW + xx] = pv;

    const float4* wp = (const float4*)w_proj;
    const float4* bp = (const float4*)b_proj;
    float4 w0 = wp[j * 2], w1 = wp[j * 2 + 1];
    float4 b0 = bp[j * 2], b1 = bp[j * 2 + 1];
    short8 o;
    o[0] = (short)f2bf(fmaxf(fmaf(pv, w0.x, b0.x), 0.f));
    o[1] = (short)f2bf(fmaxf(fmaf(pv, w0.y, b0.y), 0.f));
    o[2] = (short)f2bf(fmaxf(fmaf(pv, w0.z, b0.z), 0.f));
    o[3] = (short)f2bf(fmaxf(fmaf(pv, w0.w, b0.w), 0.f));
    o[4] = (short)f2bf(fmaxf(fmaf(pv, w1.x, b1.x), 0.f));
    o[5] = (short)f2bf(fmaxf(fmaf(pv, w1.y, b1.y), 0.f));
    o[6] = (short)f2bf(fmaxf(fmaf(pv, w1.z, b1.z), 0.f));
    o[7] = (short)f2bf(fmaxf(fmaf(pv, w1.w, b1.w), 0.f));
    *(short8*)(cur_out + pix * FF + j * 8) = o;
}

extern "C" void kernel_launch(void* const* d_in, const int* in_sizes, int n_in,
                              void* d_out, int out_size, void* d_ws, size_t ws_size,
                              hipStream_t stream)
{
    const float* x      = (const float*)d_in[0];
    const float* wk     = (const float*)d_in[1];
    const float* wr     = (const float*)d_in[2];
    const float* bias   = (const float*)d_in[3];
    const float* w_out  = (const float*)d_in[4];
    const float* b_out  = (const float*)d_in[5];
    const float* w_proj = (const float*)d_in[6];
    const float* b_proj = (const float*)d_in[7];
    float* out = (float*)d_out;

    const size_t SB = (size_t)BB * HH * WW * FF;   // 8388608 elems
    unsigned short* h_a = (unsigned short*)d_ws;
    unsigned short* h_b = h_a + SB;
    float* cb = (float*)((char*)d_ws + 2 * SB * sizeof(unsigned short));
    short8* packed = (short8*)((char*)cb + SB * sizeof(float));  // 19456*16 B

    pack_wr<<<76, 256, 0, stream>>>(wr, wk, bias, packed);

    const int NBLK_STEP = (WW / TW) * (HH / 2) * BB;   // 1024 (double-row blocks)
    const int NBLK_DEC  = (WW / TWD) * HH * BB;        // 4096
    unsigned short* bufs[2] = {h_a, h_b};
    // FIRST writes every c/h element before any read -> no memset needed.
    lstm_step_mfma<true><<<NBLK_STEP, 512, 0, stream>>>(x, 0, bufs[0], cb, bufs[1], packed);
    for (int t = 1; t < TT; ++t) {
        lstm_step_mfma<false><<<NBLK_STEP, 512, 0, stream>>>(x, t, bufs[t & 1], cb,
                                                             bufs[(t + 1) & 1], packed);
    }

    for (int ti = 0; ti < PRED_LEN; ++ti) {
        dec_fused<<<NBLK_DEC, 256, 0, stream>>>(
            bufs[ti & 1], w_out, b_out, w_proj, b_proj, out, bufs[(ti + 1) & 1], ti);
    }
}

// Round 12
// 749.597 us; speedup vs baseline: 10.6961x; 10.6961x over previous
//
#include <hip/hip_runtime.h>
#include <math.h>

#define BB 8
#define TT 12
#define HH 128
#define WW 128
#define FF 64
#define GG 256   // 4*FF
#define PRED_LEN 6
#define TW 64     // pixels per block along W (step kernel)
#define TWD 32    // pixels per block along W (decoder)

typedef __attribute__((ext_vector_type(8))) short short8;
typedef __attribute__((ext_vector_type(4))) float floatx4;

__device__ __forceinline__ float sigf(float x) { return 1.f / (1.f + __expf(-x)); }
__device__ __forceinline__ float tanhfast(float x) { return 1.f - 2.f / (__expf(2.f * x) + 1.f); }

__device__ __forceinline__ unsigned short f2bf(float x) {
    unsigned u = __float_as_uint(x);
    u = (u + 0x7FFFu + ((u >> 16) & 1u)) >> 16;
    return (unsigned short)u;
}

// async global->LDS, 16B per lane; LDS dest = wave-uniform base + lane*16.
__device__ __forceinline__ void gload_lds16(const void* g, void* l) {
    __builtin_amdgcn_global_load_lds(
        (const __attribute__((address_space(1))) unsigned int*)g,
        (__attribute__((address_space(3))) unsigned int*)l,
        16, 0, 0);
}

// Step-grid XCD swizzle: 1024 blocks, one batch per XCD, y-contiguous
// (R8-proven L2 locality).
__device__ __forceinline__ void decode_step(int wg, int& b, int& y, int& x0) {
    int lin = (wg & 7) * 128 + (wg >> 3);   // [0,1024)
    b = lin >> 7;                           // 128 blocks per batch
    int rem = lin & 127;
    y = (rem >> 1) * 2;                     // y-pair base row
    x0 = (rem & 1) * TW;
}

// Decoder swizzle (R6/R7-proven): 4096 blocks.
__device__ __forceinline__ void decode_dec(int wg, int& b, int& y, int& x0) {
    int lin = (wg & 7) * 512 + (wg >> 3);
    b = lin >> 9;
    int rem = lin & 511;
    y = rem >> 2;
    x0 = (rem & 3) * TWD;
}

// Pack B-fragments for mfma_f32_16x16x32_bf16.  (R5-proven, unchanged.)
__global__ __launch_bounds__(256) void pack_wr(
    const float* __restrict__ wr, const float* __restrict__ wk,
    const float* __restrict__ bias, short8* __restrict__ packed)
{
    int e = blockIdx.x * 256 + threadIdx.x;   // 19456 entries
    if (e >= 19 * 16 * 64) return;
    int lane = e & 63;
    int rest = e >> 6;
    int nt = rest & 15;
    int ch = rest >> 4;        // 0..18
    int col = lane & 15, kpart = lane >> 4;
    int n = nt * 16 + col;
    short8 v;
    if (ch < 18) {
        int kc = ch & 1, tap = ch >> 1;
        #pragma unroll
        for (int j = 0; j < 8; ++j) {
            int k = kc * 32 + kpart * 8 + j;
            v[j] = (short)f2bf(wr[((size_t)(tap * 64 + k)) * GG + n]);
        }
    } else {
        #pragma unroll
        for (int j = 0; j < 8; ++j) {
            int k = kpart * 8 + j;
            unsigned short r = 0;
            if (k < 9) r = f2bf(wk[k * GG + n]);
            else if (k == 9) r = f2bf(bias[n]);   // bias row (A has 1.0 there)
            v[j] = (short)r;
        }
    }
    packed[e] = v;
}

// Fused ConvLSTM step, double-row blocks (R9) + pipelined B via LDS ring (R11).
// Block = 512 threads = 8 waves: waves 0-3 row y, waves 4-7 row y+1.
// 38 half-phases; wave w prefetches N-tile w of phase p+1 via global_load_lds
// while computing phase p (counted vmcnt(1), never drained) -> B's L2 latency
// hides under MFMA. Numerics bit-identical to R9.
template<bool FIRST>
__global__ __launch_bounds__(512, 4) void lstm_step_mfma(
    const float* __restrict__ x,             // (B,T,H,W,1) fp32
    int t,
    const unsigned short* __restrict__ h_in, // (B,H,W,F) bf16
    float* __restrict__ c_buf,               // (B,H,W,F) fp32 in/out
    unsigned short* __restrict__ h_out,      // (B,H,W,F) bf16
    const short8* __restrict__ packedB)      // packed wr | wk+bias
{
    __shared__ __align__(16) unsigned short sh[4 * 66 * FF];  // swizzled bf16 h rows y-1..y+2
    __shared__ __align__(16) unsigned short sxa[2][TW * 32];  // swizzled x A-frags per row
    __shared__ __align__(16) short8 ldsB[2][8 * 64];          // B half-chunk ring (2 x 8KB)
    __shared__ float sx[4][66];

    const int tid = threadIdx.x;
    int b, y, x0;
    decode_step(blockIdx.x, b, y, x0);
    char* shb = (char*)sh;

    if (!FIRST) {
        // stage h tile: 4 rows x 66 cols x 64 ch bf16, 16B chunks, XOR-swizzled
        for (int i = tid; i < 4 * 66 * 8; i += 512) {
            int cq  = i & 7;
            int rc  = i >> 3;
            int col = rc % 66, r = rc / 66;
            int gy = y + r - 1, gx = x0 + col - 1;
            uint4 v = make_uint4(0u, 0u, 0u, 0u);
            if ((unsigned)gy < HH && (unsigned)gx < WW)
                v = *(const uint4*)(h_in + ((((size_t)b * HH + gy) * WW + gx) * FF + cq * 8));
            int byte = ((r * 66 + col) * FF + cq * 8) * 2;
            byte ^= ((col & 7) << 4);
            *(uint4*)(shb + byte) = v;
        }
    }
    // stage x tile (fp32), 4 rows
    for (int i = tid; i < 4 * 66; i += 512) {
        int col = i % 66, r = i / 66;
        int gy = y + r - 1, gx = x0 + col - 1;
        float v = 0.f;
        if ((unsigned)gy < HH && (unsigned)gx < WW)
            v = x[(((size_t)b * TT + t) * HH + gy) * WW + gx];
        sx[r][col] = v;
    }
    __syncthreads();

    // build x A-fragment tiles (one per row): sxa[rr][px][k]
    {
        int rr  = tid >> 8;        // row tile 0/1
        int t2  = tid & 255;
        int px  = t2 >> 2, kpc = t2 & 3;
        short8 v;
        #pragma unroll
        for (int j = 0; j < 8; ++j) {
            int k = kpc * 8 + j;
            unsigned short r = 0;
            if (k < 9) r = f2bf(sx[rr + k / 3][px + (k % 3)]);
            else if (k == 9) r = (unsigned short)0x3F80;   // 1.0 multiplies bias row
            v[j] = (short)r;
        }
        int byte = (px * 64 + kpc * 16) ^ ((px & 7) << 4);
        *(short8*)((char*)sxa[rr] + byte) = v;
    }
    __syncthreads();

    const int l    = tid & 63;
    const int w    = tid >> 6;     // 0..7
    const int sw   = w & 3;        // sub-wave role
    const int rrow = w >> 2;       // which row of the pair
    const int lc = l & 15;
    const int kp = l >> 4;
    const int gcol = sw * 16 + lc;   // feature index 0..63
    const size_t base = (((size_t)b * HH + (y + rrow)) * WW + x0) * FF + gcol;

    floatx4 acc[4][4];
    #pragma unroll
    for (int m = 0; m < 4; ++m)
        #pragma unroll
        for (int q = 0; q < 4; ++q)
            acc[m][q] = (floatx4){0.f, 0.f, 0.f, 0.f};

    // ---- pipelined chunk loop: 38 half-phases (19 chunks x 2 halves) ----
    // phase hc: chunk c=hc>>1, half=hc&1 -> gates q = half*2+{0,1},
    // B N-tiles (q*4+sw); wave w stages local N-tile w for phase hc+1.
    constexpr int HC0 = FIRST ? 36 : 0;
    {   // prologue: stage phase HC0
        constexpr int c1 = HC0 >> 1, h1 = HC0 & 1;
        gload_lds16(packedB + ((size_t)(c1 * 16 + h1 * 8 + w) * 64 + l),
                    &ldsB[HC0 & 1][w * 64]);
    }
    asm volatile("s_waitcnt vmcnt(0)" ::: "memory");
    __builtin_amdgcn_s_barrier();
    __builtin_amdgcn_sched_barrier(0);

    short8 af[4];
    #pragma unroll
    for (int hc = HC0; hc < 38; ++hc) {
        const int c = hc >> 1, half = hc & 1, buf = hc & 1;
        if (hc + 1 < 38) {
            const int c1 = (hc + 1) >> 1, h1 = (hc + 1) & 1;
            gload_lds16(packedB + ((size_t)(c1 * 16 + h1 * 8 + w) * 64 + l),
                        &ldsB[(hc + 1) & 1][w * 64]);
            asm volatile("s_waitcnt vmcnt(1)" ::: "memory");  // counted: keep 1 in flight
        } else {
            asm volatile("s_waitcnt vmcnt(0)" ::: "memory");
        }
        __builtin_amdgcn_s_barrier();            // all waves' phase-hc B landed
        __builtin_amdgcn_sched_barrier(0);       // don't hoist ds_reads above

        if (half == 0) {                         // af shared by both halves of chunk c
            if (c < 18) {
                const int tap_ = c >> 1, kc_ = c & 1, dy_ = tap_ / 3, dx_ = tap_ % 3;
                #pragma unroll
                for (int m_ = 0; m_ < 4; ++m_) {
                    const int col_ = m_ * 16 + lc + dx_;
                    int byte_ = (((dy_ + rrow) * 66 + col_) * FF + kc_ * 32 + kp * 8) * 2;
                    byte_ ^= ((col_ & 7) << 4);
                    af[m_] = *(const short8*)(shb + byte_);
                }
            } else {
                #pragma unroll
                for (int m_ = 0; m_ < 4; ++m_) {
                    const int px_ = m_ * 16 + lc;
                    int byte_ = (px_ * 64 + kp * 16) ^ ((px_ & 7) << 4);
                    af[m_] = *(const short8*)((const char*)sxa[rrow] + byte_);
                }
            }
        }
        short8 bf0 = ldsB[buf][(0 + sw) * 64 + l];
        short8 bf1 = ldsB[buf][(4 + sw) * 64 + l];
        const int q0 = half * 2, q1 = half * 2 + 1;
        #pragma unroll
        for (int m_ = 0; m_ < 4; ++m_) {
            acc[m_][q0] = __builtin_amdgcn_mfma_f32_16x16x32_bf16(af[m_], bf0, acc[m_][q0], 0, 0, 0);
            acc[m_][q1] = __builtin_amdgcn_mfma_f32_16x16x32_bf16(af[m_], bf1, acc[m_][q1], 0, 0, 0);
        }
        __builtin_amdgcn_s_barrier();            // reads done before ring overwrite
    }

    // epilogue: gates + cell update (Keras order i,f,g,o)
    #pragma unroll
    for (int m = 0; m < 4; ++m) {
        #pragma unroll
        for (int r = 0; r < 4; ++r) {
            int p = m * 16 + kp * 4 + r;   // pixel within tile
            size_t idx = base + (size_t)p * FF;
            float cpv = FIRST ? 0.f : c_buf[idx];
            float iv = sigf(acc[m][0][r]);
            float fv = sigf(acc[m][1][r]);
            float gv = tanhfast(acc[m][2][r]);
            float ov = sigf(acc[m][3][r]);
            float cn = fv * cpv + iv * gv;
            float hn = ov * tanhfast(cn);
            c_buf[idx] = cn;
            h_out[idx] = f2bf(hn);
        }
    }
}

// Fused decoder iteration (R6/R7-proven):
__global__ __launch_bounds__(256) void dec_fused(
    const unsigned short* __restrict__ cur_in, const float* __restrict__ w_out,
    const float* __restrict__ b_out, const float* __restrict__ w_proj,
    const float* __restrict__ b_proj, float* __restrict__ out,
    unsigned short* __restrict__ cur_out, int ti)
{
    int tid = threadIdx.x;
    int j  = tid & 7;
    int pp = tid >> 3;
    int b, y, x0;
    decode_dec(blockIdx.x, b, y, x0);
    int xx = x0 + pp;

    float s = 0.f;
    for (int dy = 0; dy < 3; ++dy) {
        int gy = y + dy - 1;
        if ((unsigned)gy >= HH) continue;
        #pragma unroll
        for (int dx = 0; dx < 3; ++dx) {
            int gx = xx + dx - 1;
            if ((unsigned)gx >= WW) continue;
            const uint4 cv = *(const uint4*)(cur_in + ((((size_t)b * HH + gy) * WW + gx) * FF + j * 8));
            const float4* wp = (const float4*)&w_out[(dy * 3 + dx) * FF + j * 8];
            float4 w0 = wp[0], w1 = wp[1];
            unsigned cx = cv.x, cy = cv.y, cz = cv.z, cw = cv.w;
            s += __uint_as_float(cx << 16) * w0.x + __uint_as_float(cx & 0xFFFF0000u) * w0.y
               + __uint_as_float(cy << 16) * w0.z + __uint_as_float(cy & 0xFFFF0000u) * w0.w
               + __uint_as_float(cz << 16) * w1.x + __uint_as_float(cz & 0xFFFF0000u) * w1.y
               + __uint_as_float(cw << 16) * w1.z + __uint_as_float(cw & 0xFFFF0000u) * w1.w;
        }
    }
    s += __shfl_xor(s, 1);
    s += __shfl_xor(s, 2);
    s += __shfl_xor(s, 4);
    float pv = sigf(s + b_out[0]);

    size_t pix = (((size_t)b * HH + y) * WW + xx);
    if (j == 0)
        out[((size_t)b * PRED_LEN + ti) * (HH * WW) + (size_t)y * WW + xx] = pv;

    const float4* wp = (const float4*)w_proj;
    const float4* bp = (const float4*)b_proj;
    float4 w0 = wp[j * 2], w1 = wp[j * 2 + 1];
    float4 b0 = bp[j * 2], b1 = bp[j * 2 + 1];
    short8 o;
    o[0] = (short)f2bf(fmaxf(fmaf(pv, w0.x, b0.x), 0.f));
    o[1] = (short)f2bf(fmaxf(fmaf(pv, w0.y, b0.y), 0.f));
    o[2] = (short)f2bf(fmaxf(fmaf(pv, w0.z, b0.z), 0.f));
    o[3] = (short)f2bf(fmaxf(fmaf(pv, w0.w, b0.w), 0.f));
    o[4] = (short)f2bf(fmaxf(fmaf(pv, w1.x, b1.x), 0.f));
    o[5] = (short)f2bf(fmaxf(fmaf(pv, w1.y, b1.y), 0.f));
    o[6] = (short)f2bf(fmaxf(fmaf(pv, w1.z, b1.z), 0.f));
    o[7] = (short)f2bf(fmaxf(fmaf(pv, w1.w, b1.w), 0.f));
    *(short8*)(cur_out + pix * FF + j * 8) = o;
}

extern "C" void kernel_launch(void* const* d_in, const int* in_sizes, int n_in,
                              void* d_out, int out_size, void* d_ws, size_t ws_size,
                              hipStream_t stream)
{
    const float* x      = (const float*)d_in[0];
    const float* wk     = (const float*)d_in[1];
    const float* wr     = (const float*)d_in[2];
    const float* bias   = (const float*)d_in[3];
    const float* w_out  = (const float*)d_in[4];
    const float* b_out  = (const float*)d_in[5];
    const float* w_proj = (const float*)d_in[6];
    const float* b_proj = (const float*)d_in[7];
    float* out = (float*)d_out;

    const size_t SB = (size_t)BB * HH * WW * FF;   // 8388608 elems
    unsigned short* h_a = (unsigned short*)d_ws;
    unsigned short* h_b = h_a + SB;
    float* cb = (float*)((char*)d_ws + 2 * SB * sizeof(unsigned short));
    short8* packed = (short8*)((char*)cb + SB * sizeof(float));  // 19456*16 B

    pack_wr<<<76, 256, 0, stream>>>(wr, wk, bias, packed);

    const int NBLK_STEP = (WW / TW) * (HH / 2) * BB;   // 1024 (double-row blocks)
    const int NBLK_DEC  = (WW / TWD) * HH * BB;        // 4096
    unsigned short* bufs[2] = {h_a, h_b};
    // FIRST writes every c/h element before any read -> no memset needed.
    lstm_step_mfma<true><<<NBLK_STEP, 512, 0, stream>>>(x, 0, bufs[0], cb, bufs[1], packed);
    for (int t = 1; t < TT; ++t) {
        lstm_step_mfma<false><<<NBLK_STEP, 512, 0, stream>>>(x, t, bufs[t & 1], cb,
                                                             bufs[(t + 1) & 1], packed);
    }

    for (int ti = 0; ti < PRED_LEN; ++ti) {
        dec_fused<<<NBLK_DEC, 256, 0, stream>>>(
            bufs[ti & 1], w_out, b_out, w_proj, b_proj, out, bufs[(ti + 1) & 1], ti);
    }
}